// Round 5
// baseline (132.848 us; speedup 1.0000x reference)
//
#include <hip/hip_runtime.h>

// B=128, H=W=28 (HW=784), C=128.
// ref: per-(b,c) spatial argmax of x -> gather t_p[c, h*, w*] (a [28,28] tile)
// -> outputs (relu(x*t), x, t) each [B,H,W,C], concatenated in d_out.
//
// R5: single fused kernel, per-batch producer/consumer sync via agent-scope
// atomics. grid (14,128) = 1792 blocks = 7 blocks/CU (co-resident by
// __launch_bounds__(256,7)). Each block:
//   P1: argmax partial for its (b, 56-s chunk) + nt-write ox; publish partial
//       (agent atomics) + magic flag (release).
//   P2: poll b's 14 flags (lanes 0..13); timeout -> recompute missing chunk
//       locally (correct under ANY dispatch order; no deadlock possible).
//   P3: gather t_p (nt), write om/ot (nt); x re-read is L1/L2-hot.
// Flag staleness across replays is benign: partials are a pure function of x,
// so stale-flagged data is byte-identical. Poison 0xAAAAAAAA != magic.

constexpr int HWc = 784, Cc = 128, Bc = 128;
constexpr int NCH = 14, CHS = 56;
constexpr unsigned MAGICBASE = 0x5A170000u;  // | gid (gid < 1792 < 2^16)

typedef float f4 __attribute__((ext_vector_type(4)));
typedef int i4 __attribute__((ext_vector_type(4)));

__device__ inline void nt_store(float* p, f4 v) {
  __builtin_nontemporal_store(v, (f4*)p);
}
__device__ inline f4 nt_load4(const float* p) {
  return __builtin_nontemporal_load((const f4*)p);
}

__global__ __launch_bounds__(256, 7) void fused_pc(
    const float* __restrict__ x, const float* __restrict__ tp,
    float* __restrict__ out, float* __restrict__ wmax, int* __restrict__ widx,
    unsigned* __restrict__ wflag) {
  const int sx = blockIdx.x;  // 0..13 spatial chunk
  const int b = blockIdx.y;
  const int t = threadIdx.x;
  const int c4 = t & 31, ch = c4 << 2, part = t >> 5;  // part/u: 0..7
  const size_t plane = (size_t)HWc * Cc;
  const size_t bplane = (size_t)b * plane;

  __shared__ float smax[8][Cc];
  __shared__ int sidx[8][Cc];
  __shared__ int tbase[Cc];
  __shared__ int lready[NCH];

  float* om = out;
  float* oxs = out + (size_t)Bc * plane;
  float* ots = out + 2 * (size_t)Bc * plane;

  // ---- P1: own-chunk argmax partial (8 parts x 7 s) + ox copy ----
  {
    int s0 = sx * CHS + part * 7;
    const float* xrow = x + bplane + ch;
    float* oxrow = oxs + bplane + ch;
    f4 best = {-3.4e38f, -3.4e38f, -3.4e38f, -3.4e38f};
    i4 bi = {s0, s0, s0, s0};
#pragma unroll
    for (int k = 0; k < 7; ++k) {
      int s = s0 + k;
      f4 v = *(const f4*)(xrow + (size_t)s * Cc);
      nt_store(oxrow + (size_t)s * Cc, v);
      if (v[0] > best[0]) { best[0] = v[0]; bi[0] = s; }
      if (v[1] > best[1]) { best[1] = v[1]; bi[1] = s; }
      if (v[2] > best[2]) { best[2] = v[2]; bi[2] = s; }
      if (v[3] > best[3]) { best[3] = v[3]; bi[3] = s; }
    }
    *(f4*)&smax[part][ch] = best;
    *(i4*)&sidx[part][ch] = bi;
  }
  __syncthreads();

  // reduce 8 parts (ascending s; strict > keeps earliest), publish
  if (t < Cc) {
    float m = smax[0][t];
    int mi = sidx[0][t];
#pragma unroll
    for (int p = 1; p < 8; ++p) {
      float v = smax[p][t];
      if (v > m) { m = v; mi = sidx[p][t]; }
    }
    int g = (b * NCH + sx) * Cc + t;
    __hip_atomic_store(&wmax[g], m, __ATOMIC_RELAXED, __HIP_MEMORY_SCOPE_AGENT);
    __hip_atomic_store(&widx[g], mi, __ATOMIC_RELAXED, __HIP_MEMORY_SCOPE_AGENT);
  }
  __syncthreads();  // compiler drains outstanding stores (vmcnt) at barrier
  if (t == 0) {
    unsigned gid = (unsigned)(b * NCH + sx);
    __hip_atomic_store(&wflag[gid], MAGICBASE | gid, __ATOMIC_RELEASE,
                       __HIP_MEMORY_SCOPE_AGENT);
  }

  // ---- P2: poll 14 flags (lanes 0..13), merge partials ----
  if (t < NCH) {
    unsigned gid = (unsigned)(b * NCH + t);
    unsigned want = MAGICBASE | gid;
    int ok = 0;
    for (int it = 0; it < 3000; ++it) {
      if (__hip_atomic_load(&wflag[gid], __ATOMIC_ACQUIRE,
                            __HIP_MEMORY_SCOPE_AGENT) == want) {
        ok = 1;
        break;
      }
      __builtin_amdgcn_s_sleep(1);
    }
    lready[t] = ok;
  }
  __syncthreads();

  if (t < Cc) {
    float m = -3.4e38f;
    int mi = 0;
    for (int j = 0; j < NCH; ++j) {
      if (lready[j]) {
        int g = (b * NCH + j) * Cc + t;
        float v =
            __hip_atomic_load(&wmax[g], __ATOMIC_RELAXED, __HIP_MEMORY_SCOPE_AGENT);
        int vi =
            __hip_atomic_load(&widx[g], __ATOMIC_RELAXED, __HIP_MEMORY_SCOPE_AGENT);
        if (v > m || (v == m && vi < mi)) { m = v; mi = vi; }  // first-max
      } else {
        // fallback: recompute chunk j (ascending s, strict >) — rare path
        const float* xc = x + bplane + t;
        for (int s = j * CHS; s < j * CHS + CHS; ++s) {
          float v = xc[(size_t)s * Cc];
          if (v > m) { m = v; mi = s; }
        }
      }
    }
    tbase[t] = (t * HWc + mi) * HWc;
  }
  __syncthreads();

  // ---- P3: gather t, write om/ot for own chunk (x is L1/L2-hot) ----
  const float* r0 = tp + tbase[ch + 0];
  const float* r1 = tp + tbase[ch + 1];
  const float* r2 = tp + tbase[ch + 2];
  const float* r3 = tp + tbase[ch + 3];
  int sb = sx * CHS;

#pragma unroll
  for (int k = 0; k < 2; ++k) {
    int idx = part + (k << 3);
    if (idx < NCH) {
      int s0 = sb + (idx << 2);
      size_t off = bplane + (size_t)s0 * Cc + ch;
      const float* xp2 = x + off;

      f4 xv0 = *(const f4*)(xp2);
      f4 xv1 = *(const f4*)(xp2 + Cc);
      f4 xv2 = *(const f4*)(xp2 + 2 * Cc);
      f4 xv3 = *(const f4*)(xp2 + 3 * Cc);
      f4 tv0 = nt_load4(r0 + s0);
      f4 tv1 = nt_load4(r1 + s0);
      f4 tv2 = nt_load4(r2 + s0);
      f4 tv3 = nt_load4(r3 + s0);

      float* omp = om + off;
      float* otp = ots + off;
#pragma unroll
      for (int i = 0; i < 4; ++i) {
        f4 xvi = (i == 0) ? xv0 : (i == 1) ? xv1 : (i == 2) ? xv2 : xv3;
        f4 tc = {tv0[i], tv1[i], tv2[i], tv3[i]};
        f4 mv;
        mv[0] = fmaxf(xvi[0] * tc[0], 0.f);
        mv[1] = fmaxf(xvi[1] * tc[1], 0.f);
        mv[2] = fmaxf(xvi[2] * tc[2], 0.f);
        mv[3] = fmaxf(xvi[3] * tc[3], 0.f);
        nt_store(omp + i * Cc, mv);
        nt_store(otp + i * Cc, tc);
      }
    }
  }
}

// ---------------- fallback path (ws too small): R4 two-kernel ----------------
__global__ __launch_bounds__(512) void argmax_copy_kernel(
    const float* __restrict__ x, float* __restrict__ ox,
    float* __restrict__ pmax, int* __restrict__ pidx) {
  int chunk = blockIdx.x, b = blockIdx.y, t = threadIdx.x;
  int c4 = t & 31, part = t >> 5, ch = c4 << 2;
  int cbase = chunk * 392;
  int s0 = cbase + part * 25;
  int send = s0 + 25;
  if (send > cbase + 392) send = cbase + 392;
  const size_t plane = (size_t)HWc * Cc;
  const float* xp = x + (size_t)b * plane + ch;
  float* oxp = ox + (size_t)b * plane + ch;
  f4 best = {-3.4e38f, -3.4e38f, -3.4e38f, -3.4e38f};
  i4 bi = {s0, s0, s0, s0};
  for (int s = s0; s < send; ++s) {
    f4 v = *(const f4*)(xp + (size_t)s * Cc);
    nt_store(oxp + (size_t)s * Cc, v);
    if (v[0] > best[0]) { best[0] = v[0]; bi[0] = s; }
    if (v[1] > best[1]) { best[1] = v[1]; bi[1] = s; }
    if (v[2] > best[2]) { best[2] = v[2]; bi[2] = s; }
    if (v[3] > best[3]) { best[3] = v[3]; bi[3] = s; }
  }
  __shared__ float smax[16][Cc];
  __shared__ int sidx[16][Cc];
  *(f4*)&smax[part][ch] = best;
  *(i4*)&sidx[part][ch] = bi;
  __syncthreads();
  if (t < Cc) {
    float m = smax[0][t];
    int mi = sidx[0][t];
#pragma unroll
    for (int p = 1; p < 16; ++p) {
      float v = smax[p][t];
      if (v > m) { m = v; mi = sidx[p][t]; }
    }
    int o = (b * 2 + chunk) * Cc + t;
    pmax[o] = m;
    pidx[o] = mi;
  }
}

__global__ __launch_bounds__(256) void out_kernel(
    const float* __restrict__ x, const float* __restrict__ tp,
    const float* __restrict__ pmax, const int* __restrict__ pidx,
    float* __restrict__ out) {
  int b = blockIdx.y, t = threadIdx.x;
  __shared__ int tbase[Cc];
  if (t < Cc) {
    int base = b * 2 * Cc + t;
    float m = pmax[base];
    int mi = pidx[base];
    float v = pmax[base + Cc];
    if (v > m) { m = v; mi = pidx[base + Cc]; }
    tbase[t] = (t * HWc + mi) * HWc;
  }
  __syncthreads();
  int c4 = t & 31, u = t >> 5, ch = c4 << 2;
  const float* r0 = tp + tbase[ch + 0];
  const float* r1 = tp + tbase[ch + 1];
  const float* r2 = tp + tbase[ch + 2];
  const float* r3 = tp + tbase[ch + 3];
  const size_t plane = (size_t)HWc * Cc;
  size_t bplane = (size_t)b * plane;
  float* om = out;
  float* ot = out + 2 * (size_t)Bc * plane;
  int sb = blockIdx.x * 56;
#pragma unroll
  for (int k = 0; k < 2; ++k) {
    int idx = u + (k << 3);
    if (idx < 14) {
      int s0 = sb + (idx << 2);
      size_t off = bplane + (size_t)s0 * Cc + ch;
      const float* xp = x + off;
      f4 xv0 = *(const f4*)(xp);
      f4 xv1 = *(const f4*)(xp + Cc);
      f4 xv2 = *(const f4*)(xp + 2 * Cc);
      f4 xv3 = *(const f4*)(xp + 3 * Cc);
      f4 tv0 = *(const f4*)(r0 + s0);
      f4 tv1 = *(const f4*)(r1 + s0);
      f4 tv2 = *(const f4*)(r2 + s0);
      f4 tv3 = *(const f4*)(r3 + s0);
      float* omp = om + off;
      float* otp = ot + off;
#pragma unroll
      for (int i = 0; i < 4; ++i) {
        f4 xvi = (i == 0) ? xv0 : (i == 1) ? xv1 : (i == 2) ? xv2 : xv3;
        f4 tc = {tv0[i], tv1[i], tv2[i], tv3[i]};
        f4 mv;
        mv[0] = fmaxf(xvi[0] * tc[0], 0.f);
        mv[1] = fmaxf(xvi[1] * tc[1], 0.f);
        mv[2] = fmaxf(xvi[2] * tc[2], 0.f);
        mv[3] = fmaxf(xvi[3] * tc[3], 0.f);
        nt_store(omp + i * Cc, mv);
        nt_store(otp + i * Cc, tc);
      }
    }
  }
}

extern "C" void kernel_launch(void* const* d_in, const int* in_sizes, int n_in,
                              void* d_out, int out_size, void* d_ws,
                              size_t ws_size, hipStream_t stream) {
  const float* x = (const float*)d_in[0];
  const float* tp = (const float*)d_in[1];
  float* out = (float*)d_out;

  const size_t npart = (size_t)Bc * NCH * Cc;  // 229376
  const size_t need = npart * 8 + (size_t)Bc * NCH * 4;

  if (ws_size >= need) {
    float* wmax = (float*)d_ws;
    int* widx = (int*)((char*)d_ws + npart * 4);
    unsigned* wflag = (unsigned*)((char*)d_ws + npart * 8);
    fused_pc<<<dim3(NCH, Bc), 256, 0, stream>>>(x, tp, out, wmax, widx, wflag);
  } else {
    float* ox = out + (size_t)Bc * HWc * Cc;
    float* pmax = (float*)d_ws;
    int* pidx = (int*)((char*)d_ws + (size_t)Bc * 2 * Cc * sizeof(float));
    argmax_copy_kernel<<<dim3(2, Bc), 512, 0, stream>>>(x, ox, pmax, pidx);
    out_kernel<<<dim3(14, Bc), 256, 0, stream>>>(x, tp, pmax, pidx, out);
  }
}

// Round 6
// 72.415 us; speedup vs baseline: 1.8345x; 1.8345x over previous
//
#include <hip/hip_runtime.h>

// B=128, H=W=28 (HW=784), C=128.
// ref: per-(b,c) spatial argmax of x -> gather t_p[c, h*, w*] (a [28,28] tile)
// -> outputs (relu(x*t), x, t) each [B,H,W,C], concatenated in d_out.
//
// R6 structure (two kernels, no inter-block sync — R3/R5 lesson):
//  K1: grid (4,B) x 512. argmax partials (4 chunks x 196 s) + nt-writes the ox
//      slab while x is in registers. 16 waves/CU.
//  K2: grid (28,B) x 256. finalize argmax; STAGE t_p slice via LDS:
//      dense along-row global loads (16 full lines/instr) -> LDS transpose ->
//      ds_read_b128 [s][c] reads. Kills the 4x line-touch amplification of
//      the direct c-mapped gather. Outputs nt-stored.

constexpr int HWc = 784, Cc = 128, Bc = 128;
constexpr int K1S = 196;   // s per K1 chunk (4 chunks)
constexpr int K2S = 28;    // s per K2 block (28 blocks per b)
constexpr int LDW = 132;   // padded LDS row stride (floats): 16B-aligned rows,
                           // write banks (16*s4+4i+c)%32 -> 2-way (free)

typedef float f4 __attribute__((ext_vector_type(4)));
typedef int i4 __attribute__((ext_vector_type(4)));

__device__ inline void nt_store(float* p, f4 v) {
  __builtin_nontemporal_store(v, (f4*)p);
}
__device__ inline f4 nt_load4(const float* p) {
  return __builtin_nontemporal_load((const f4*)p);
}

// ---------------------------------------------------------------------------
// K1: argmax partials + ox copy. Thread: c4 = t&31 (4 channels), part = t>>5
// (16 parts x <=13 s). Strict '>' ascending-s keeps JAX first-max semantics.
// ---------------------------------------------------------------------------
__global__ __launch_bounds__(512) void argmax_copy_kernel(
    const float* __restrict__ x, float* __restrict__ ox,
    float* __restrict__ pmax, int* __restrict__ pidx) {
  int chunk = blockIdx.x;  // 0..3
  int b = blockIdx.y;
  int t = threadIdx.x;
  int c4 = t & 31, part = t >> 5, ch = c4 << 2;

  int cbase = chunk * K1S;
  int s0 = cbase + part * 13;
  int send = s0 + 13;
  if (send > cbase + K1S) send = cbase + K1S;  // part 15: 1 iter

  const size_t plane = (size_t)HWc * Cc;
  const float* xp = x + (size_t)b * plane + ch;
  float* oxp = ox + (size_t)b * plane + ch;

  f4 best = {-3.4e38f, -3.4e38f, -3.4e38f, -3.4e38f};
  i4 bi = {s0, s0, s0, s0};
  for (int s = s0; s < send; ++s) {
    f4 v = *(const f4*)(xp + (size_t)s * Cc);
    nt_store(oxp + (size_t)s * Cc, v);
    if (v[0] > best[0]) { best[0] = v[0]; bi[0] = s; }
    if (v[1] > best[1]) { best[1] = v[1]; bi[1] = s; }
    if (v[2] > best[2]) { best[2] = v[2]; bi[2] = s; }
    if (v[3] > best[3]) { best[3] = v[3]; bi[3] = s; }
  }

  __shared__ float smax[16][Cc];
  __shared__ int sidx[16][Cc];
  *(f4*)&smax[part][ch] = best;
  *(i4*)&sidx[part][ch] = bi;
  __syncthreads();

  if (t < Cc) {
    float m = smax[0][t];
    int mi = sidx[0][t];
#pragma unroll
    for (int p = 1; p < 16; ++p) {
      float v = smax[p][t];
      if (v > m) { m = v; mi = sidx[p][t]; }  // strict >: earliest s wins
    }
    int o = (b * 4 + chunk) * Cc + t;
    pmax[o] = m;
    pidx[o] = mi;
  }
}

// ---------------------------------------------------------------------------
// K2: finalize argmax, LDS-stage t slice, write om/ot.
// ---------------------------------------------------------------------------
__global__ __launch_bounds__(256) void out_kernel(
    const float* __restrict__ x, const float* __restrict__ tp,
    const float* __restrict__ pmax, const int* __restrict__ pidx,
    float* __restrict__ out) {
  int sx = blockIdx.x;  // 0..27
  int b = blockIdx.y;
  int t = threadIdx.x;
  int sb = sx * K2S;

  __shared__ int tbase[Cc];
  __shared__ float tl[K2S * LDW];  // 14.8 KB

  // ---- A: finalize argmax from 4 partials (ascending chunk, strict >) ----
  if (t < Cc) {
    int base = b * 4 * Cc + t;
    float m = pmax[base];
    int mi = pidx[base];
#pragma unroll
    for (int p = 1; p < 4; ++p) {
      float v = pmax[base + p * Cc];
      if (v > m) { m = v; mi = pidx[base + p * Cc]; }
    }
    tbase[t] = (t * HWc + mi) * HWc;
  }
  __syncthreads();

  // ---- B: stage t slice [28 s][128 c] into LDS ----
  // thread: c0 = t>>2 (0..63), q = t&3; 2 channel batches; per (batch,j):
  // wave instr = 16 rows x 64B contiguous = 16 fully-consumed lines.
  {
    int c0 = t >> 2, q = t & 3;
#pragma unroll
    for (int batch = 0; batch < 2; ++batch) {
      int c = c0 + (batch << 6);
      const float* row = tp + tbase[c] + sb;
#pragma unroll
      for (int j = 0; j < 2; ++j) {
        int s4 = q + (j << 2);
        if (s4 < 7) {
          f4 v = nt_load4(row + (s4 << 2));
          int sl = s4 << 2;
          tl[(sl + 0) * LDW + c] = v[0];
          tl[(sl + 1) * LDW + c] = v[1];
          tl[(sl + 2) * LDW + c] = v[2];
          tl[(sl + 3) * LDW + c] = v[3];
        }
      }
    }
  }
  __syncthreads();

  // ---- C: compute + store. thread (c4, u): u<7 handles s0 = sb + 4u ----
  int c4 = t & 31, u = t >> 5, ch = c4 << 2;
  if (u < 7) {
    const size_t plane = (size_t)HWc * Cc;
    size_t bplane = (size_t)b * plane;
    int s0 = sb + (u << 2);
    size_t off = bplane + (size_t)s0 * Cc + ch;
    const float* xp = x + off;

    f4 xv0 = *(const f4*)(xp);
    f4 xv1 = *(const f4*)(xp + Cc);
    f4 xv2 = *(const f4*)(xp + 2 * Cc);
    f4 xv3 = *(const f4*)(xp + 3 * Cc);

    int sl = u << 2;
    f4 tc0 = *(const f4*)&tl[(sl + 0) * LDW + ch];
    f4 tc1 = *(const f4*)&tl[(sl + 1) * LDW + ch];
    f4 tc2 = *(const f4*)&tl[(sl + 2) * LDW + ch];
    f4 tc3 = *(const f4*)&tl[(sl + 3) * LDW + ch];

    float* omp = out + off;
    float* otp = out + 2 * (size_t)Bc * plane + off;

#pragma unroll
    for (int i = 0; i < 4; ++i) {
      f4 xvi = (i == 0) ? xv0 : (i == 1) ? xv1 : (i == 2) ? xv2 : xv3;
      f4 tc = (i == 0) ? tc0 : (i == 1) ? tc1 : (i == 2) ? tc2 : tc3;
      f4 mv;
      mv[0] = fmaxf(xvi[0] * tc[0], 0.f);
      mv[1] = fmaxf(xvi[1] * tc[1], 0.f);
      mv[2] = fmaxf(xvi[2] * tc[2], 0.f);
      mv[3] = fmaxf(xvi[3] * tc[3], 0.f);
      nt_store(omp + i * Cc, mv);
      nt_store(otp + i * Cc, tc);
    }
  }
}

extern "C" void kernel_launch(void* const* d_in, const int* in_sizes, int n_in,
                              void* d_out, int out_size, void* d_ws,
                              size_t ws_size, hipStream_t stream) {
  const float* x = (const float*)d_in[0];
  const float* tp = (const float*)d_in[1];
  float* out = (float*)d_out;
  float* ox = out + (size_t)Bc * HWc * Cc;  // slab 1: x copy, written by K1

  // workspace: pmax[B*4*C] floats + pidx[B*4*C] ints = 512 KB
  float* pmax = (float*)d_ws;
  int* pidx = (int*)((char*)d_ws + (size_t)Bc * 4 * Cc * sizeof(float));

  argmax_copy_kernel<<<dim3(4, Bc), 512, 0, stream>>>(x, ox, pmax, pidx);
  out_kernel<<<dim3(28, Bc), 256, 0, stream>>>(x, tp, pmax, pidx, out);
}

// Round 7
// 71.382 us; speedup vs baseline: 1.8611x; 1.0145x over previous
//
#include <hip/hip_runtime.h>

// B=128, H=W=28 (HW=784), C=128.
// ref: per-(b,c) spatial argmax of x -> gather t_p[c, h*, w*] (a [28,28] tile)
// -> outputs (relu(x*t), x, t) each [B,H,W,C], concatenated in d_out.
//
// R7 = R4 skeleton (proven 56.9us) + L3-locality knobs:
//  K1: grid (2,B) x 512. argmax partials + nt-writes ox slab. x loads plain
//      (allocate L3 for K2's re-read).
//  K2: grid (14,B) x 256, b REVERSED (LRU-aligned with K1's tail; ping-pongs
//      across graph replays). t_p loads nontemporal (read-once, don't evict
//      x from L3). Outputs nt-stored.

constexpr int HWc = 784, Cc = 128, Bc = 128;

typedef float f4 __attribute__((ext_vector_type(4)));
typedef int i4 __attribute__((ext_vector_type(4)));

__device__ inline void nt_store(float* p, f4 v) {
  __builtin_nontemporal_store(v, (f4*)p);
}
__device__ inline f4 nt_load4(const float* p) {
  return __builtin_nontemporal_load((const f4*)p);
}

// ---------------------------------------------------------------------------
// K1: grid (2, B), 512 threads. Thread: c4 = t&31 (channels 4c4..4c4+3),
// part = t>>5 (16 parts x <=25 s). Reads x (float4, coalesced, plain),
// updates per-channel argmax, nt-stores the x copy to ox.
// Strict '>' in ascending-s order preserves JAX first-max tie semantics.
// ---------------------------------------------------------------------------
__global__ __launch_bounds__(512) void argmax_copy_kernel(
    const float* __restrict__ x, float* __restrict__ ox,
    float* __restrict__ pmax, int* __restrict__ pidx) {
  int chunk = blockIdx.x;  // 0..1
  int b = blockIdx.y;
  int t = threadIdx.x;
  int c4 = t & 31;
  int part = t >> 5;  // 0..15
  int ch = c4 << 2;

  int cbase = chunk * 392;
  int s0 = cbase + part * 25;
  int send = s0 + 25;
  if (send > cbase + 392) send = cbase + 392;  // part 15: 17 iters

  const size_t plane = (size_t)HWc * Cc;
  const float* xp = x + (size_t)b * plane + ch;
  float* oxp = ox + (size_t)b * plane + ch;

  f4 best = {-3.4e38f, -3.4e38f, -3.4e38f, -3.4e38f};
  i4 bi = {s0, s0, s0, s0};
  for (int s = s0; s < send; ++s) {
    f4 v = *(const f4*)(xp + (size_t)s * Cc);
    nt_store(oxp + (size_t)s * Cc, v);
    if (v[0] > best[0]) { best[0] = v[0]; bi[0] = s; }
    if (v[1] > best[1]) { best[1] = v[1]; bi[1] = s; }
    if (v[2] > best[2]) { best[2] = v[2]; bi[2] = s; }
    if (v[3] > best[3]) { best[3] = v[3]; bi[3] = s; }
  }

  __shared__ float smax[16][Cc];
  __shared__ int sidx[16][Cc];
  *(f4*)&smax[part][ch] = best;
  *(i4*)&sidx[part][ch] = bi;
  __syncthreads();

  if (t < Cc) {
    float m = smax[0][t];
    int mi = sidx[0][t];
#pragma unroll
    for (int p = 1; p < 16; ++p) {
      float v = smax[p][t];
      if (v > m) { m = v; mi = sidx[p][t]; }  // strict >: earliest s wins
    }
    int o = (b * 2 + chunk) * Cc + t;
    pmax[o] = m;
    pidx[o] = mi;
  }
}

// ---------------------------------------------------------------------------
// K2: finalize argmax (2 partials), write om and ot. b reversed vs K1.
// grid (14, B), 256 threads: c4 = t&31, u = t>>5 (0..7), k = 0..1,
// idx = u + 8k < 14 (guard is wave-uniform). 4s x 4c register tile:
// 4 float4 x loads (plain; L3-hot by reversed order), 4 float4 t loads
// along s (nontemporal), register transpose, 8 float4 nt stores.
// ---------------------------------------------------------------------------
__global__ __launch_bounds__(256) void out_kernel(
    const float* __restrict__ x, const float* __restrict__ tp,
    const float* __restrict__ pmax, const int* __restrict__ pidx,
    float* __restrict__ out) {
  int b = (Bc - 1) - blockIdx.y;  // reversed: LRU-aligned with K1's tail
  int t = threadIdx.x;

  __shared__ int tbase[Cc];  // per-channel t_p row base in floats (<2^31)
  if (t < Cc) {
    int base = b * 2 * Cc + t;
    float m = pmax[base];
    int mi = pidx[base];
    float v = pmax[base + Cc];
    if (v > m) { m = v; mi = pidx[base + Cc]; }
    tbase[t] = (t * HWc + mi) * HWc;
  }
  __syncthreads();

  int c4 = t & 31;
  int u = t >> 5;
  int ch = c4 << 2;

  const float* r0 = tp + tbase[ch + 0];
  const float* r1 = tp + tbase[ch + 1];
  const float* r2 = tp + tbase[ch + 2];
  const float* r3 = tp + tbase[ch + 3];

  const size_t plane = (size_t)HWc * Cc;
  size_t bplane = (size_t)b * plane;
  float* om = out;                           // relu(x*t)
  float* ot = out + 2 * (size_t)Bc * plane;  // templates (ox written by K1)
  int sb = blockIdx.x * 56;

#pragma unroll
  for (int k = 0; k < 2; ++k) {
    int idx = u + (k << 3);
    if (idx < 14) {
      int s0 = sb + (idx << 2);
      size_t off = bplane + (size_t)s0 * Cc + ch;
      const float* xp = x + off;

      f4 xv0 = *(const f4*)(xp);
      f4 xv1 = *(const f4*)(xp + Cc);
      f4 xv2 = *(const f4*)(xp + 2 * Cc);
      f4 xv3 = *(const f4*)(xp + 3 * Cc);
      f4 tv0 = nt_load4(r0 + s0);
      f4 tv1 = nt_load4(r1 + s0);
      f4 tv2 = nt_load4(r2 + s0);
      f4 tv3 = nt_load4(r3 + s0);

      float* omp = om + off;
      float* otp = ot + off;

#pragma unroll
      for (int i = 0; i < 4; ++i) {
        f4 xvi = (i == 0) ? xv0 : (i == 1) ? xv1 : (i == 2) ? xv2 : xv3;
        f4 tcol = {tv0[i], tv1[i], tv2[i], tv3[i]};
        f4 mv;
        mv[0] = fmaxf(xvi[0] * tcol[0], 0.f);
        mv[1] = fmaxf(xvi[1] * tcol[1], 0.f);
        mv[2] = fmaxf(xvi[2] * tcol[2], 0.f);
        mv[3] = fmaxf(xvi[3] * tcol[3], 0.f);
        nt_store(omp + i * Cc, mv);
        nt_store(otp + i * Cc, tcol);
      }
    }
  }
}

extern "C" void kernel_launch(void* const* d_in, const int* in_sizes, int n_in,
                              void* d_out, int out_size, void* d_ws,
                              size_t ws_size, hipStream_t stream) {
  const float* x = (const float*)d_in[0];
  const float* tp = (const float*)d_in[1];
  float* out = (float*)d_out;
  float* ox = out + (size_t)Bc * HWc * Cc;  // slab 1: x copy, written by K1

  // workspace: pmax[B*2*C] floats + pidx[B*2*C] ints = 256 KB
  float* pmax = (float*)d_ws;
  int* pidx = (int*)((char*)d_ws + (size_t)Bc * 2 * Cc * sizeof(float));

  argmax_copy_kernel<<<dim3(2, Bc), 512, 0, stream>>>(x, ox, pmax, pidx);
  out_kernel<<<dim3(14, Bc), 256, 0, stream>>>(x, tp, pmax, pidx, out);
}

// Round 8
// 61.359 us; speedup vs baseline: 2.1651x; 1.1634x over previous
//
#include <hip/hip_runtime.h>

// B=128, H=W=28 (HW=784), C=128.
// ref: per-(b,c) spatial argmax of x -> gather t_p[c, h*, w*] (a [28,28] tile)
// -> outputs (relu(x*t), x, t) each [B,H,W,C], concatenated in d_out.
//
// R8 = R4 skeleton (proven 56.9us) with ONE knob flipped: all stores PLAIN
// (nt_store removed). A/B: nt stores were never isolated; fills (plain
// stores) achieve 7 TB/s, our nt-store kernels ~5-6 TB/s effective.
// t_p loads plain (R7 lesson: nt loads amplify gather traffic 4x).

constexpr int HWc = 784, Cc = 128, Bc = 128;

typedef float f4 __attribute__((ext_vector_type(4)));
typedef int i4 __attribute__((ext_vector_type(4)));

// ---------------------------------------------------------------------------
// K1: grid (2, B), 512 threads. Thread: c4 = t&31 (channels 4c4..4c4+3),
// part = t>>5 (16 parts x <=25 s). Reads x (float4, coalesced), updates
// per-channel argmax, stores the x copy to ox.
// Strict '>' in ascending-s order preserves JAX first-max tie semantics.
// ---------------------------------------------------------------------------
__global__ __launch_bounds__(512) void argmax_copy_kernel(
    const float* __restrict__ x, float* __restrict__ ox,
    float* __restrict__ pmax, int* __restrict__ pidx) {
  int chunk = blockIdx.x;  // 0..1
  int b = blockIdx.y;
  int t = threadIdx.x;
  int c4 = t & 31;
  int part = t >> 5;  // 0..15
  int ch = c4 << 2;

  int cbase = chunk * 392;
  int s0 = cbase + part * 25;
  int send = s0 + 25;
  if (send > cbase + 392) send = cbase + 392;  // part 15: 17 iters

  const size_t plane = (size_t)HWc * Cc;
  const float* xp = x + (size_t)b * plane + ch;
  float* oxp = ox + (size_t)b * plane + ch;

  f4 best = {-3.4e38f, -3.4e38f, -3.4e38f, -3.4e38f};
  i4 bi = {s0, s0, s0, s0};
  for (int s = s0; s < send; ++s) {
    f4 v = *(const f4*)(xp + (size_t)s * Cc);
    *(f4*)(oxp + (size_t)s * Cc) = v;
    if (v[0] > best[0]) { best[0] = v[0]; bi[0] = s; }
    if (v[1] > best[1]) { best[1] = v[1]; bi[1] = s; }
    if (v[2] > best[2]) { best[2] = v[2]; bi[2] = s; }
    if (v[3] > best[3]) { best[3] = v[3]; bi[3] = s; }
  }

  __shared__ float smax[16][Cc];
  __shared__ int sidx[16][Cc];
  *(f4*)&smax[part][ch] = best;
  *(i4*)&sidx[part][ch] = bi;
  __syncthreads();

  if (t < Cc) {
    float m = smax[0][t];
    int mi = sidx[0][t];
#pragma unroll
    for (int p = 1; p < 16; ++p) {
      float v = smax[p][t];
      if (v > m) { m = v; mi = sidx[p][t]; }  // strict >: earliest s wins
    }
    int o = (b * 2 + chunk) * Cc + t;
    pmax[o] = m;
    pidx[o] = mi;
  }
}

// ---------------------------------------------------------------------------
// K2: finalize argmax (2 partials), write om and ot.
// grid (14, B), 256 threads: c4 = t&31, u = t>>5 (0..7), k = 0..1,
// idx = u + 8k < 14 (guard is wave-uniform). 4s x 4c register tile:
// 4 float4 x loads (L3-hot from K1), 4 float4 t loads along s (plain;
// L2 coalesces the 4x16B pieces of each line), register transpose,
// 8 float4 plain stores.
// ---------------------------------------------------------------------------
__global__ __launch_bounds__(256) void out_kernel(
    const float* __restrict__ x, const float* __restrict__ tp,
    const float* __restrict__ pmax, const int* __restrict__ pidx,
    float* __restrict__ out) {
  int b = blockIdx.y;
  int t = threadIdx.x;

  __shared__ int tbase[Cc];  // per-channel t_p row base in floats (<2^31)
  if (t < Cc) {
    int base = b * 2 * Cc + t;
    float m = pmax[base];
    int mi = pidx[base];
    float v = pmax[base + Cc];
    if (v > m) { m = v; mi = pidx[base + Cc]; }
    tbase[t] = (t * HWc + mi) * HWc;
  }
  __syncthreads();

  int c4 = t & 31;
  int u = t >> 5;
  int ch = c4 << 2;

  const float* r0 = tp + tbase[ch + 0];
  const float* r1 = tp + tbase[ch + 1];
  const float* r2 = tp + tbase[ch + 2];
  const float* r3 = tp + tbase[ch + 3];

  const size_t plane = (size_t)HWc * Cc;
  size_t bplane = (size_t)b * plane;
  float* om = out;                           // relu(x*t)
  float* ot = out + 2 * (size_t)Bc * plane;  // templates (ox written by K1)
  int sb = blockIdx.x * 56;

#pragma unroll
  for (int k = 0; k < 2; ++k) {
    int idx = u + (k << 3);
    if (idx < 14) {
      int s0 = sb + (idx << 2);
      size_t off = bplane + (size_t)s0 * Cc + ch;
      const float* xp = x + off;

      f4 xv0 = *(const f4*)(xp);
      f4 xv1 = *(const f4*)(xp + Cc);
      f4 xv2 = *(const f4*)(xp + 2 * Cc);
      f4 xv3 = *(const f4*)(xp + 3 * Cc);
      f4 tv0 = *(const f4*)(r0 + s0);
      f4 tv1 = *(const f4*)(r1 + s0);
      f4 tv2 = *(const f4*)(r2 + s0);
      f4 tv3 = *(const f4*)(r3 + s0);

      float* omp = om + off;
      float* otp = ot + off;

#pragma unroll
      for (int i = 0; i < 4; ++i) {
        f4 xvi = (i == 0) ? xv0 : (i == 1) ? xv1 : (i == 2) ? xv2 : xv3;
        f4 tcol = {tv0[i], tv1[i], tv2[i], tv3[i]};
        f4 mv;
        mv[0] = fmaxf(xvi[0] * tcol[0], 0.f);
        mv[1] = fmaxf(xvi[1] * tcol[1], 0.f);
        mv[2] = fmaxf(xvi[2] * tcol[2], 0.f);
        mv[3] = fmaxf(xvi[3] * tcol[3], 0.f);
        *(f4*)(omp + i * Cc) = mv;
        *(f4*)(otp + i * Cc) = tcol;
      }
    }
  }
}

extern "C" void kernel_launch(void* const* d_in, const int* in_sizes, int n_in,
                              void* d_out, int out_size, void* d_ws,
                              size_t ws_size, hipStream_t stream) {
  const float* x = (const float*)d_in[0];
  const float* tp = (const float*)d_in[1];
  float* out = (float*)d_out;
  float* ox = out + (size_t)Bc * HWc * Cc;  // slab 1: x copy, written by K1

  // workspace: pmax[B*2*C] floats + pidx[B*2*C] ints = 256 KB
  float* pmax = (float*)d_ws;
  int* pidx = (int*)((char*)d_ws + (size_t)Bc * 2 * Cc * sizeof(float));

  argmax_copy_kernel<<<dim3(2, Bc), 512, 0, stream>>>(x, ox, pmax, pidx);
  out_kernel<<<dim3(14, Bc), 256, 0, stream>>>(x, tp, pmax, pidx, out);
}

// Round 9
// 57.138 us; speedup vs baseline: 2.3251x; 1.0739x over previous
//
#include <hip/hip_runtime.h>

// B=128, H=W=28 (HW=784), C=128.
// ref: per-(b,c) spatial argmax of x -> gather t_p[c, h*, w*] (a [28,28] tile)
// -> outputs (relu(x*t), x, t) each [B,H,W,C], concatenated in d_out.
//
// R9 = R4 config (nt stores, plain t_p loads — both A/B-proven) with ONE
// knob: K1 occupancy 8 -> 16 waves/CU (grid (4,B) x 512 = 2 blocks/CU).
//  K1: argmax partials (4 chunks x 196 s) + nt-writes ox slab.
//  K2: grid (14,B) x 256 (7 blocks/CU). finalize argmax (4 partials),
//      gather t (plain loads), write om/ot (nt stores).

constexpr int HWc = 784, Cc = 128, Bc = 128;
constexpr int K1S = 196;  // s per K1 chunk (4 chunks per b)

typedef float f4 __attribute__((ext_vector_type(4)));
typedef int i4 __attribute__((ext_vector_type(4)));

__device__ inline void nt_store(float* p, f4 v) {
  __builtin_nontemporal_store(v, (f4*)p);
}

// ---------------------------------------------------------------------------
// K1: grid (4, B), 512 threads. Thread: c4 = t&31 (channels 4c4..4c4+3),
// part = t>>5 (16 parts; parts 0..11 get 12 s, 12..15 get 13 s — balanced,
// ascending). Reads x (float4, plain), nt-stores the x copy to ox, updates
// per-channel argmax. Strict '>' ascending-s keeps JAX first-max semantics.
// ---------------------------------------------------------------------------
__global__ __launch_bounds__(512) void argmax_copy_kernel(
    const float* __restrict__ x, float* __restrict__ ox,
    float* __restrict__ pmax, int* __restrict__ pidx) {
  int chunk = blockIdx.x;  // 0..3
  int b = blockIdx.y;
  int t = threadIdx.x;
  int c4 = t & 31;
  int part = t >> 5;  // 0..15
  int ch = c4 << 2;

  int cbase = chunk * K1S;
  int s0 = cbase + part * 12 + (part > 12 ? part - 12 : 0);
  int per = (part < 12) ? 12 : 13;
  int send = s0 + per;

  const size_t plane = (size_t)HWc * Cc;
  const float* xp = x + (size_t)b * plane + ch;
  float* oxp = ox + (size_t)b * plane + ch;

  f4 best = {-3.4e38f, -3.4e38f, -3.4e38f, -3.4e38f};
  i4 bi = {s0, s0, s0, s0};
  for (int s = s0; s < send; ++s) {
    f4 v = *(const f4*)(xp + (size_t)s * Cc);
    nt_store(oxp + (size_t)s * Cc, v);
    if (v[0] > best[0]) { best[0] = v[0]; bi[0] = s; }
    if (v[1] > best[1]) { best[1] = v[1]; bi[1] = s; }
    if (v[2] > best[2]) { best[2] = v[2]; bi[2] = s; }
    if (v[3] > best[3]) { best[3] = v[3]; bi[3] = s; }
  }

  __shared__ float smax[16][Cc];
  __shared__ int sidx[16][Cc];
  *(f4*)&smax[part][ch] = best;
  *(i4*)&sidx[part][ch] = bi;
  __syncthreads();

  if (t < Cc) {
    float m = smax[0][t];
    int mi = sidx[0][t];
#pragma unroll
    for (int p = 1; p < 16; ++p) {
      float v = smax[p][t];
      if (v > m) { m = v; mi = sidx[p][t]; }  // strict >: earliest s wins
    }
    int o = (b * 4 + chunk) * Cc + t;
    pmax[o] = m;
    pidx[o] = mi;
  }
}

// ---------------------------------------------------------------------------
// K2: finalize argmax (4 partials, ascending chunk order), write om and ot.
// grid (14, B), 256 threads: c4 = t&31, u = t>>5 (0..7), idx = u + 8k < 14.
// 4s x 4c register tile: 4 float4 x loads (L3-hot), 4 float4 t loads along s
// (plain — L2 coalesces line pieces), register transpose, 8 nt stores.
// ---------------------------------------------------------------------------
__global__ __launch_bounds__(256) void out_kernel(
    const float* __restrict__ x, const float* __restrict__ tp,
    const float* __restrict__ pmax, const int* __restrict__ pidx,
    float* __restrict__ out) {
  int b = blockIdx.y;
  int t = threadIdx.x;

  __shared__ int tbase[Cc];  // per-channel t_p row base in floats (<2^31)
  if (t < Cc) {
    int base = b * 4 * Cc + t;
    float m = pmax[base];
    int mi = pidx[base];
#pragma unroll
    for (int p = 1; p < 4; ++p) {
      float v = pmax[base + p * Cc];
      if (v > m) { m = v; mi = pidx[base + p * Cc]; }
    }
    tbase[t] = (t * HWc + mi) * HWc;
  }
  __syncthreads();

  int c4 = t & 31;
  int u = t >> 5;
  int ch = c4 << 2;

  const float* r0 = tp + tbase[ch + 0];
  const float* r1 = tp + tbase[ch + 1];
  const float* r2 = tp + tbase[ch + 2];
  const float* r3 = tp + tbase[ch + 3];

  const size_t plane = (size_t)HWc * Cc;
  size_t bplane = (size_t)b * plane;
  float* om = out;                           // relu(x*t)
  float* ot = out + 2 * (size_t)Bc * plane;  // templates (ox written by K1)
  int sb = blockIdx.x * 56;

#pragma unroll
  for (int k = 0; k < 2; ++k) {
    int idx = u + (k << 3);
    if (idx < 14) {
      int s0 = sb + (idx << 2);
      size_t off = bplane + (size_t)s0 * Cc + ch;
      const float* xp = x + off;

      f4 xv0 = *(const f4*)(xp);
      f4 xv1 = *(const f4*)(xp + Cc);
      f4 xv2 = *(const f4*)(xp + 2 * Cc);
      f4 xv3 = *(const f4*)(xp + 3 * Cc);
      f4 tv0 = *(const f4*)(r0 + s0);
      f4 tv1 = *(const f4*)(r1 + s0);
      f4 tv2 = *(const f4*)(r2 + s0);
      f4 tv3 = *(const f4*)(r3 + s0);

      float* omp = om + off;
      float* otp = ot + off;

#pragma unroll
      for (int i = 0; i < 4; ++i) {
        f4 xvi = (i == 0) ? xv0 : (i == 1) ? xv1 : (i == 2) ? xv2 : xv3;
        f4 tcol = {tv0[i], tv1[i], tv2[i], tv3[i]};
        f4 mv;
        mv[0] = fmaxf(xvi[0] * tcol[0], 0.f);
        mv[1] = fmaxf(xvi[1] * tcol[1], 0.f);
        mv[2] = fmaxf(xvi[2] * tcol[2], 0.f);
        mv[3] = fmaxf(xvi[3] * tcol[3], 0.f);
        nt_store(omp + i * Cc, mv);
        nt_store(otp + i * Cc, tcol);
      }
    }
  }
}

extern "C" void kernel_launch(void* const* d_in, const int* in_sizes, int n_in,
                              void* d_out, int out_size, void* d_ws,
                              size_t ws_size, hipStream_t stream) {
  const float* x = (const float*)d_in[0];
  const float* tp = (const float*)d_in[1];
  float* out = (float*)d_out;
  float* ox = out + (size_t)Bc * HWc * Cc;  // slab 1: x copy, written by K1

  // workspace: pmax[B*4*C] floats + pidx[B*4*C] ints = 512 KB
  float* pmax = (float*)d_ws;
  int* pidx = (int*)((char*)d_ws + (size_t)Bc * 4 * Cc * sizeof(float));

  argmax_copy_kernel<<<dim3(4, Bc), 512, 0, stream>>>(x, ox, pmax, pidx);
  out_kernel<<<dim3(14, Bc), 256, 0, stream>>>(x, tp, pmax, pidx, out);
}